// Round 1
// baseline (221.639 us; speedup 1.0000x reference)
//
#include <hip/hip_runtime.h>
#include <hip/hip_bf16.h>
#include <math.h>

// Problem constants
#define NB 65536
#define ND 256
#define NE 16
#define NH 64
#define NA 18

typedef __bf16 bf16;
typedef __bf16 bf16x4 __attribute__((ext_vector_type(4)));
typedef __bf16 bf16x8 __attribute__((ext_vector_type(8)));
typedef float  f32x4  __attribute__((ext_vector_type(4)));

// ---- workspace layout (bytes) ----
// Wcat packed bf16 [64 kc][1024 col][8]          : 1 MB
// bcat  f32 [1024]                               : 4 KB
// PW1 packed bf16 [16 e][32 kc][128 col][8]      : 1 MB
// b1cat f32 [16][128]                            : 8 KB
// cursors int[16]                                : 64 B
// perm int [16][65536]                           : 4 MB
#define OFF_WCAT 0u
#define OFF_BCAT 1048576u
#define OFF_PW1  1052672u
#define OFF_B1   2101248u
#define OFF_CUR  2109440u
#define OFF_PERM 2109504u
// total ~6.01 MB of d_ws

__device__ __forceinline__ float sigm_(float x) {
    return 1.f / (1.f + __expf(-x));
}
__device__ __forceinline__ float tanh_(float x) {
    float cl = fminf(fmaxf(x, -15.f), 15.f);
    float e = __expf(2.f * cl);
    return (e - 1.f) / (e + 1.f);
}

// ---------------- prep1: pack LSTM weights, fuse biases, init cursors ----------------
__global__ void k_prep1(const float* __restrict__ W_ih, const float* __restrict__ W_hh,
                        const float* __restrict__ b_ih, const float* __restrict__ b_hh,
                        char* __restrict__ ws) {
    int t = blockIdx.x * 256 + threadIdx.x;        // 65536 = 64 kc * 1024 col
    bf16* Wcat = (bf16*)(ws + OFF_WCAT);
    int kc = t & 63, col = t >> 6;
    int k = kc * 8;
    const float* src = (k < 256) ? (W_ih + (size_t)col * 256 + k)
                                 : (W_hh + (size_t)col * 256 + (k - 256));
    float4 v0 = *(const float4*)(src);
    float4 v1 = *(const float4*)(src + 4);
    bf16x8 o;
    o[0] = (bf16)v0.x; o[1] = (bf16)v0.y; o[2] = (bf16)v0.z; o[3] = (bf16)v0.w;
    o[4] = (bf16)v1.x; o[5] = (bf16)v1.y; o[6] = (bf16)v1.z; o[7] = (bf16)v1.w;
    *(bf16x8*)(Wcat + ((size_t)kc * 1024 + col) * 8) = o;
    if (t < 1024) ((float*)(ws + OFF_BCAT))[t] = b_ih[t] + b_hh[t];
    if (t < 16)   ((int*)(ws + OFF_CUR))[t] = t * 65536;   // bucket cursor init (every call)
}

// ---------------- prep2: pack expert layer-1 weights (actor|critic), fuse biases ----------------
__global__ void k_prep2(const float* __restrict__ Wa1, const float* __restrict__ Wc1,
                        const float* __restrict__ ba1, const float* __restrict__ bc1,
                        char* __restrict__ ws) {
    int t = blockIdx.x * 256 + threadIdx.x;        // 65536 = 16 e * 32 kc * 128 col
    bf16* PW1 = (bf16*)(ws + OFF_PW1);
    int col = t & 127, kc = (t >> 7) & 31, e = t >> 12;
    bf16x8 o;
#pragma unroll
    for (int j = 0; j < 8; ++j) {
        int k = kc * 8 + j;
        float v = (col < 64) ? Wa1[((size_t)e * 256 + k) * 64 + col]
                             : Wc1[((size_t)e * 256 + k) * 64 + (col - 64)];
        o[j] = (bf16)v;
    }
    *(bf16x8*)(PW1 + (((size_t)e * 32 + kc) * 128 + col) * 8) = o;
    if (t < 2048) {
        int e2 = t >> 7, c = t & 127;
        ((float*)(ws + OFF_B1))[t] = (c < 64) ? ba1[e2 * 64 + c] : bc1[e2 * 64 + (c - 64)];
    }
}

// ---------------- scatter: bucket rows by expert (order-free => deterministic outputs) ----------------
__global__ void k_scatter(const int* __restrict__ idxs, char* __restrict__ ws) {
    __shared__ int lh[16], lbase[16];
    int t = threadIdx.x;
    int i = blockIdx.x * 256 + t;
    if (t < 16) lh[t] = 0;
    __syncthreads();
    int e = idxs[i];
    int r = atomicAdd(&lh[e], 1);      // rank within block; lh[e] ends as block count
    __syncthreads();
    int* cur = (int*)(ws + OFF_CUR);
    if (t < 16) lbase[t] = atomicAdd(&cur[t], lh[t]);
    __syncthreads();
    ((int*)(ws + OFF_PERM))[lbase[e] + r] = i;
}

// ---------------- k_lstm: fused gates GEMM + LSTM pointwise ----------------
// block = 64 rows x 1024 gate cols; 16 waves; wave w owns c-cols [16w,16w+16),
// n-fragments = the 4 gates => pointwise entirely in-register.
__global__ __launch_bounds__(1024) void k_lstm(
    const float* __restrict__ obs, const float* __restrict__ hin,
    const float* __restrict__ cin, const float* __restrict__ bcat,
    const bf16* __restrict__ Wcat,
    float* __restrict__ hout, float* __restrict__ cout) {
    __shared__ alignas(16) bf16 Alds[8 * 64 * 8];   // [kc][row][8] k-packed, 8KB
    const int tid  = threadIdx.x;
    const int wave = tid >> 6, lane = tid & 63;
    const int lr = lane & 15, lk = lane >> 4;
    const int row0 = blockIdx.x * 64;
    const int srow = tid >> 4, sf4 = tid & 15;

    f32x4 acc[4][4];   // [m-frag][gate]
#pragma unroll
    for (int m = 0; m < 4; ++m)
#pragma unroll
        for (int g = 0; g < 4; ++g)
#pragma unroll
            for (int r = 0; r < 4; ++r) acc[m][g][r] = 0.f;

    for (int ks = 0; ks < 8; ++ks) {
        int k0 = ks * 64;
        // stage A [64 rows][64 k] fp32->bf16, k-packed
        const float* sp = (k0 < 256)
            ? (obs + (size_t)(row0 + srow) * 256 + k0 + sf4 * 4)
            : (hin + (size_t)(row0 + srow) * 256 + (k0 - 256) + sf4 * 4);
        float4 v = *(const float4*)sp;
        bf16x4 pw;
        pw[0] = (bf16)v.x; pw[1] = (bf16)v.y; pw[2] = (bf16)v.z; pw[3] = (bf16)v.w;
        *(bf16x4*)(Alds + (((sf4 >> 1) * 64 + srow) * 8) + (sf4 & 1) * 4) = pw;
        __syncthreads();

        int kcg0 = ks * 8;
#pragma unroll
        for (int kf = 0; kf < 2; ++kf) {
            bf16x8 a[4], bb[4];
#pragma unroll
            for (int m = 0; m < 4; ++m)
                a[m] = *(const bf16x8*)(Alds + (((kf * 4 + lk) * 64) + (m * 16 + lr)) * 8);
#pragma unroll
            for (int g = 0; g < 4; ++g) {
                int col = g * 256 + wave * 16 + lr;
                int kc  = kcg0 + kf * 4 + lk;
                bb[g] = *(const bf16x8*)(Wcat + ((size_t)kc * 1024 + col) * 8);
            }
#pragma unroll
            for (int m = 0; m < 4; ++m)
#pragma unroll
                for (int g = 0; g < 4; ++g)
                    acc[m][g] = __builtin_amdgcn_mfma_f32_16x16x32_bf16(a[m], bb[g], acc[m][g], 0, 0, 0);
        }
        __syncthreads();
    }

    // pointwise LSTM: lane holds all 4 gates for (row, col)
    int col = wave * 16 + lr;
    float bi = bcat[col], bf_ = bcat[256 + col], bg = bcat[512 + col], bo = bcat[768 + col];
#pragma unroll
    for (int m = 0; m < 4; ++m) {
#pragma unroll
        for (int r = 0; r < 4; ++r) {
            int row = row0 + m * 16 + lk * 4 + r;
            float gi = acc[m][0][r] + bi;
            float gf = acc[m][1][r] + bf_;
            float gg = acc[m][2][r] + bg;
            float go = acc[m][3][r] + bo;
            float iv = sigm_(gi), fv = sigm_(gf), gv = tanh_(gg), ov = sigm_(go);
            float co = cin[(size_t)row * 256 + col];
            float cn = fv * co + iv * gv;
            float hn = ov * tanh_(cn);
            cout[(size_t)row * 256 + col] = cn;
            hout[(size_t)row * 256 + col] = hn;
        }
    }
}

// ---------------- k_expert: per-(expert, 64-row chunk) routed MLPs ----------------
__global__ __launch_bounds__(256) void k_expert(
    const float* __restrict__ Wa2, const float* __restrict__ ba2,
    const float* __restrict__ Wc2, const float* __restrict__ bc2,
    char* __restrict__ ws, const float* __restrict__ hsrc,
    float* __restrict__ lout, float* __restrict__ vout) {
    const int e = blockIdx.y;
    const int* cur = (const int*)(ws + OFF_CUR);
    int cnt = cur[e] - e * 65536;
    int r0 = blockIdx.x * 64;
    if (r0 >= cnt) return;
    int nr = min(64, cnt - r0);
    const int* permE = (const int*)(ws + OFF_PERM) + (size_t)e * 65536 + r0;

    __shared__ int rows_s[64];
    __shared__ alignas(16) char smem[128 * 66 * 4];   // 33792B: aliased A-stage / ha
    bf16*  Alds = (bf16*)smem;                        // [32 kc][64 row][8] = 32KB
    float* haF  = (float*)smem;                       // [128 col][66] fp32

    int t = threadIdx.x;
    if (t < 64) rows_s[t] = permE[(t < nr) ? t : 0];
    __syncthreads();

    { // gather h rows -> bf16 k-packed LDS
        int rowi = t >> 2, q = t & 3;
        const float* hp = hsrc + (size_t)rows_s[rowi] * 256;
#pragma unroll
        for (int s = 0; s < 8; ++s) {
            int kc = s * 4 + q;
            float4 v0 = *(const float4*)(hp + kc * 8);
            float4 v1 = *(const float4*)(hp + kc * 8 + 4);
            bf16x8 o;
            o[0] = (bf16)v0.x; o[1] = (bf16)v0.y; o[2] = (bf16)v0.z; o[3] = (bf16)v0.w;
            o[4] = (bf16)v1.x; o[5] = (bf16)v1.y; o[6] = (bf16)v1.z; o[7] = (bf16)v1.w;
            *(bf16x8*)(Alds + ((size_t)kc * 64 + rowi) * 8) = o;
        }
    }
    __syncthreads();

    const bf16* PW1 = (const bf16*)(ws + OFF_PW1) + (size_t)e * 32 * 128 * 8;
    const float* b1 = (const float*)(ws + OFF_B1) + e * 128;
    int wave = t >> 6, lane = t & 63, lr = lane & 15, lk = lane >> 4;

    f32x4 acc[4][2];   // [m][n]; cols 0..63 actor hidden, 64..127 critic hidden
#pragma unroll
    for (int m = 0; m < 4; ++m)
#pragma unroll
        for (int n = 0; n < 2; ++n)
#pragma unroll
            for (int r = 0; r < 4; ++r) acc[m][n][r] = 0.f;

#pragma unroll
    for (int kf = 0; kf < 8; ++kf) {
        bf16x8 a[4], bb[2];
#pragma unroll
        for (int m = 0; m < 4; ++m)
            a[m] = *(const bf16x8*)(Alds + (((kf * 4 + lk) * 64) + (m * 16 + lr)) * 8);
#pragma unroll
        for (int n = 0; n < 2; ++n) {
            int colh = wave * 32 + n * 16 + lr;
            int kc = kf * 4 + lk;
            bb[n] = *(const bf16x8*)(PW1 + ((size_t)kc * 128 + colh) * 8);
        }
#pragma unroll
        for (int m = 0; m < 4; ++m)
#pragma unroll
            for (int n = 0; n < 2; ++n)
                acc[m][n] = __builtin_amdgcn_mfma_f32_16x16x32_bf16(a[m], bb[n], acc[m][n], 0, 0, 0);
    }
    __syncthreads();   // A reads done before aliasing writes

    // bias + tanh -> haF[col][66]
#pragma unroll
    for (int m = 0; m < 4; ++m)
#pragma unroll
        for (int n = 0; n < 2; ++n) {
            int colh = wave * 32 + n * 16 + lr;
            float bbv = b1[colh];
#pragma unroll
            for (int r = 0; r < 4; ++r) {
                int row = m * 16 + lk * 4 + r;
                haF[colh * 66 + row] = tanh_(acc[m][n][r] + bbv);
            }
        }
    __syncthreads();

    // layer 2 (tiny, VALU)
    int row = t & 63;
    int grow = rows_s[row];
    bool valid = row < nr;
#pragma unroll
    for (int p = 0; p < 5; ++p) {
        int aI = p * 4 + (t >> 6);
        if (aI < NA) {
            float s = ba2[e * NA + aI];
            for (int hh = 0; hh < 64; ++hh)
                s += haF[hh * 66 + row] * Wa2[((size_t)e * 64 + hh) * NA + aI];
            if (valid) lout[(size_t)grow * NA + aI] = s;
        }
    }
    if (t < 64) {
        float s = bc2[e];
        for (int hh = 0; hh < 64; ++hh)
            s += haF[(64 + hh) * 66 + row] * Wc2[e * 64 + hh];
        if (valid) vout[grow] = s;
    }
}

extern "C" void kernel_launch(void* const* d_in, const int* in_sizes, int n_in,
                              void* d_out, int out_size, void* d_ws, size_t ws_size,
                              hipStream_t stream) {
    const float* obs  = (const float*)d_in[0];
    const float* h    = (const float*)d_in[1];
    const float* c    = (const float*)d_in[2];
    const int*   idxs = (const int*)d_in[3];
    const float* W_ih = (const float*)d_in[4];
    const float* W_hh = (const float*)d_in[5];
    const float* b_ih = (const float*)d_in[6];
    const float* b_hh = (const float*)d_in[7];
    const float* Wa1  = (const float*)d_in[8];
    const float* ba1  = (const float*)d_in[9];
    const float* Wa2  = (const float*)d_in[10];
    const float* ba2  = (const float*)d_in[11];
    const float* Wc1  = (const float*)d_in[12];
    const float* bc1  = (const float*)d_in[13];
    const float* Wc2  = (const float*)d_in[14];
    const float* bc2  = (const float*)d_in[15];

    float* out  = (float*)d_out;
    float* hout = out;
    float* cout = out + (size_t)NB * ND;
    float* lout = out + (size_t)2 * NB * ND;
    float* vout = lout + (size_t)NB * NA;
    char* ws = (char*)d_ws;

    k_prep1<<<dim3(256), dim3(256), 0, stream>>>(W_ih, W_hh, b_ih, b_hh, ws);
    k_prep2<<<dim3(256), dim3(256), 0, stream>>>(Wa1, Wc1, ba1, bc1, ws);
    k_scatter<<<dim3(256), dim3(256), 0, stream>>>(idxs, ws);
    k_lstm<<<dim3(1024), dim3(1024), 0, stream>>>(
        obs, h, c, (const float*)(ws + OFF_BCAT), (const bf16*)(ws + OFF_WCAT), hout, cout);
    k_expert<<<dim3(1024, 16), dim3(256), 0, stream>>>(
        Wa2, ba2, Wc2, bc2, ws, hout, lout, vout);
}

// Round 2
// 193.903 us; speedup vs baseline: 1.1430x; 1.1430x over previous
//
#include <hip/hip_runtime.h>
#include <hip/hip_bf16.h>
#include <math.h>

// Problem constants
#define NB 65536
#define ND 256
#define NE 16
#define NH 64
#define NA 18

typedef __bf16 bf16;
typedef __bf16 bf16x4 __attribute__((ext_vector_type(4)));
typedef __bf16 bf16x8 __attribute__((ext_vector_type(8)));
typedef float  f32x4  __attribute__((ext_vector_type(4)));

// ---- workspace layout (bytes) ----
#define OFF_WCAT 0u
#define OFF_BCAT 1048576u
#define OFF_PW1  1052672u
#define OFF_B1   2101248u
#define OFF_CUR  2109440u
#define OFF_PERM 2109504u

__device__ __forceinline__ float sigm_(float x) {
    return 1.f / (1.f + __expf(-x));
}
__device__ __forceinline__ float tanh_(float x) {
    float cl = fminf(fmaxf(x, -15.f), 15.f);
    float e = __expf(2.f * cl);
    return (e - 1.f) / (e + 1.f);
}

// ---------------- prep1: pack LSTM weights, fuse biases, init cursors ----------------
__global__ void k_prep1(const float* __restrict__ W_ih, const float* __restrict__ W_hh,
                        const float* __restrict__ b_ih, const float* __restrict__ b_hh,
                        char* __restrict__ ws) {
    int t = blockIdx.x * 256 + threadIdx.x;        // 65536 = 64 kc * 1024 col
    bf16* Wcat = (bf16*)(ws + OFF_WCAT);
    int kc = t & 63, col = t >> 6;
    int k = kc * 8;
    const float* src = (k < 256) ? (W_ih + (size_t)col * 256 + k)
                                 : (W_hh + (size_t)col * 256 + (k - 256));
    float4 v0 = *(const float4*)(src);
    float4 v1 = *(const float4*)(src + 4);
    bf16x8 o;
    o[0] = (bf16)v0.x; o[1] = (bf16)v0.y; o[2] = (bf16)v0.z; o[3] = (bf16)v0.w;
    o[4] = (bf16)v1.x; o[5] = (bf16)v1.y; o[6] = (bf16)v1.z; o[7] = (bf16)v1.w;
    *(bf16x8*)(Wcat + ((size_t)kc * 1024 + col) * 8) = o;
    if (t < 1024) ((float*)(ws + OFF_BCAT))[t] = b_ih[t] + b_hh[t];
    if (t < 16)   ((int*)(ws + OFF_CUR))[t] = t * 65536;   // bucket cursor init (every call)
}

// ---------------- prep2: pack expert layer-1 weights (actor|critic), fuse biases ----------------
__global__ void k_prep2(const float* __restrict__ Wa1, const float* __restrict__ Wc1,
                        const float* __restrict__ ba1, const float* __restrict__ bc1,
                        char* __restrict__ ws) {
    int t = blockIdx.x * 256 + threadIdx.x;        // 65536 = 16 e * 32 kc * 128 col
    bf16* PW1 = (bf16*)(ws + OFF_PW1);
    int col = t & 127, kc = (t >> 7) & 31, e = t >> 12;
    bf16x8 o;
#pragma unroll
    for (int j = 0; j < 8; ++j) {
        int k = kc * 8 + j;
        float v = (col < 64) ? Wa1[((size_t)e * 256 + k) * 64 + col]
                             : Wc1[((size_t)e * 256 + k) * 64 + (col - 64)];
        o[j] = (bf16)v;
    }
    *(bf16x8*)(PW1 + (((size_t)e * 32 + kc) * 128 + col) * 8) = o;
    if (t < 2048) {
        int e2 = t >> 7, c = t & 127;
        ((float*)(ws + OFF_B1))[t] = (c < 64) ? ba1[e2 * 64 + c] : bc1[e2 * 64 + (c - 64)];
    }
}

// ---------------- scatter: bucket rows by expert (order-free => deterministic outputs) ----------------
__global__ void k_scatter(const int* __restrict__ idxs, char* __restrict__ ws) {
    __shared__ int lh[16], lbase[16];
    int t = threadIdx.x;
    int i = blockIdx.x * 256 + t;
    if (t < 16) lh[t] = 0;
    __syncthreads();
    int e = idxs[i];
    int r = atomicAdd(&lh[e], 1);
    __syncthreads();
    int* cur = (int*)(ws + OFF_CUR);
    if (t < 16) lbase[t] = atomicAdd(&cur[t], lh[t]);
    __syncthreads();
    ((int*)(ws + OFF_PERM))[lbase[e] + r] = i;
}

// ---------------- k_lstm v2: 2-phase pipelined, double-buffered, XOR-swizzled ----------------
// 512 thr (8 waves); block = 64 rows x 128 c-cols (x4 gates = 512 gate-cols).
// Wave w owns c-cols [chalf*128 + 16w, +16); n-frags = the 4 gates (pointwise in-register).
// Per ks (64 k): issue next-tile loads -> compute cur buffer -> cvt+ds_write other -> ONE barrier.
__global__ __launch_bounds__(512, 4) void k_lstm(
    const float* __restrict__ obs, const float* __restrict__ hin,
    const float* __restrict__ cin, const float* __restrict__ bcat,
    const bf16* __restrict__ Wcat,
    float* __restrict__ hout, float* __restrict__ cout) {
    __shared__ alignas(16) char Asmem[2][8192];   // [kc 8][row 64][8 bf16], XOR-swizzled
    const int tid  = threadIdx.x;
    const int wave = tid >> 6, lane = tid & 63;
    const int lr = lane & 15, lk = lane >> 4;
    const int rb = blockIdx.x & 1023, chalf = blockIdx.x >> 10;
    const int row0 = rb * 64;
    const int srow = tid >> 3, sf = tid & 7;        // stager: row, k-octet
    const int colc = chalf * 128 + wave * 16 + lr;  // this lane's c-column

    // LDS byte offsets, swizzle: byte = kc*1024 + ((row ^ kc)*16)
    const int wbyte = sf * 1024 + ((srow ^ sf) * 16);
    int rbo[2][4];
#pragma unroll
    for (int kf = 0; kf < 2; ++kf)
#pragma unroll
        for (int m = 0; m < 4; ++m) {
            int kc = kf * 4 + lk, R = m * 16 + lr;
            rbo[kf][m] = kc * 1024 + ((R ^ kc) * 16);
        }

    const float* pObs = obs + (size_t)(row0 + srow) * 256 + sf * 8;
    const float* pH   = hin + (size_t)(row0 + srow) * 256 + sf * 8;
    const bf16*  pB   = Wcat + ((size_t)lk * 1024 + colc) * 8;

    f32x4 acc[4][4];   // [m-frag][gate]
#pragma unroll
    for (int m = 0; m < 4; ++m)
#pragma unroll
        for (int g = 0; g < 4; ++g)
#pragma unroll
            for (int r = 0; r < 4; ++r) acc[m][g][r] = 0.f;

    // prologue: stage tile 0 into buf 0
    {
        float4 v0 = *(const float4*)pObs;
        float4 v1 = *(const float4*)(pObs + 4);
        bf16x8 o;
        o[0] = (bf16)v0.x; o[1] = (bf16)v0.y; o[2] = (bf16)v0.z; o[3] = (bf16)v0.w;
        o[4] = (bf16)v1.x; o[5] = (bf16)v1.y; o[6] = (bf16)v1.z; o[7] = (bf16)v1.w;
        *(bf16x8*)(&Asmem[0][wbyte]) = o;
    }
    __syncthreads();

#pragma unroll
    for (int ks = 0; ks < 8; ++ks) {
        const int cur = ks & 1;
        // issue next-tile loads early (latency hides under MFMA below)
        float4 n0, n1;
        if (ks < 7) {
            const float* sp = (ks < 3) ? (pObs + (ks + 1) * 64) : (pH + (ks - 3) * 64);
            n0 = *(const float4*)sp;
            n1 = *(const float4*)(sp + 4);
        }
        const char* Ab = Asmem[cur];
#pragma unroll
        for (int kf = 0; kf < 2; ++kf) {
            bf16x8 a[4];
#pragma unroll
            for (int m = 0; m < 4; ++m)
                a[m] = *(const bf16x8*)(Ab + rbo[kf][m]);
            const bf16* pBk = pB + (size_t)(ks * 8 + kf * 4) * 1024 * 8;
            bf16x8 b0 = *(const bf16x8*)(pBk);
            bf16x8 b1 = *(const bf16x8*)(pBk + 256 * 8);
            bf16x8 b2 = *(const bf16x8*)(pBk + 512 * 8);
            bf16x8 b3 = *(const bf16x8*)(pBk + 768 * 8);
#pragma unroll
            for (int m = 0; m < 4; ++m) {
                acc[m][0] = __builtin_amdgcn_mfma_f32_16x16x32_bf16(a[m], b0, acc[m][0], 0, 0, 0);
                acc[m][1] = __builtin_amdgcn_mfma_f32_16x16x32_bf16(a[m], b1, acc[m][1], 0, 0, 0);
                acc[m][2] = __builtin_amdgcn_mfma_f32_16x16x32_bf16(a[m], b2, acc[m][2], 0, 0, 0);
                acc[m][3] = __builtin_amdgcn_mfma_f32_16x16x32_bf16(a[m], b3, acc[m][3], 0, 0, 0);
            }
        }
        if (ks < 7) {
            bf16x8 o;
            o[0] = (bf16)n0.x; o[1] = (bf16)n0.y; o[2] = (bf16)n0.z; o[3] = (bf16)n0.w;
            o[4] = (bf16)n1.x; o[5] = (bf16)n1.y; o[6] = (bf16)n1.z; o[7] = (bf16)n1.w;
            *(bf16x8*)(&Asmem[cur ^ 1][wbyte]) = o;
            __syncthreads();
        }
    }

    // pointwise LSTM: lane holds all 4 gates for (row, colc)
    float bi = bcat[colc], bf_ = bcat[256 + colc], bg = bcat[512 + colc], bo = bcat[768 + colc];
#pragma unroll
    for (int m = 0; m < 4; ++m) {
#pragma unroll
        for (int r = 0; r < 4; ++r) {
            int row = row0 + m * 16 + lk * 4 + r;
            float gi = acc[m][0][r] + bi;
            float gf = acc[m][1][r] + bf_;
            float gg = acc[m][2][r] + bg;
            float go = acc[m][3][r] + bo;
            float iv = sigm_(gi), fv = sigm_(gf), gv = tanh_(gg), ov = sigm_(go);
            float co = cin[(size_t)row * 256 + colc];
            float cn = fv * co + iv * gv;
            float hn = ov * tanh_(cn);
            cout[(size_t)row * 256 + colc] = cn;
            hout[(size_t)row * 256 + colc] = hn;
        }
    }
}

// ---------------- k_expert: per-(expert, 64-row chunk) routed MLPs ----------------
__global__ __launch_bounds__(256) void k_expert(
    const float* __restrict__ Wa2, const float* __restrict__ ba2,
    const float* __restrict__ Wc2, const float* __restrict__ bc2,
    char* __restrict__ ws, const float* __restrict__ hsrc,
    float* __restrict__ lout, float* __restrict__ vout) {
    const int e = blockIdx.y;
    const int* cur = (const int*)(ws + OFF_CUR);
    int cnt = cur[e] - e * 65536;
    int r0 = blockIdx.x * 64;
    if (r0 >= cnt) return;
    int nr = min(64, cnt - r0);
    const int* permE = (const int*)(ws + OFF_PERM) + (size_t)e * 65536 + r0;

    __shared__ int rows_s[64];
    __shared__ alignas(16) char smem[128 * 66 * 4];
    bf16*  Alds = (bf16*)smem;                        // [32 kc][64 row][8]
    float* haF  = (float*)smem;                       // [128 col][66]

    int t = threadIdx.x;
    if (t < 64) rows_s[t] = permE[(t < nr) ? t : 0];
    __syncthreads();

    { // gather h rows -> bf16 k-packed LDS
        int rowi = t >> 2, q = t & 3;
        const float* hp = hsrc + (size_t)rows_s[rowi] * 256;
#pragma unroll
        for (int s = 0; s < 8; ++s) {
            int kc = s * 4 + q;
            float4 v0 = *(const float4*)(hp + kc * 8);
            float4 v1 = *(const float4*)(hp + kc * 8 + 4);
            bf16x8 o;
            o[0] = (bf16)v0.x; o[1] = (bf16)v0.y; o[2] = (bf16)v0.z; o[3] = (bf16)v0.w;
            o[4] = (bf16)v1.x; o[5] = (bf16)v1.y; o[6] = (bf16)v1.z; o[7] = (bf16)v1.w;
            *(bf16x8*)(Alds + ((size_t)kc * 64 + rowi) * 8) = o;
        }
    }
    __syncthreads();

    const bf16* PW1 = (const bf16*)(ws + OFF_PW1) + (size_t)e * 32 * 128 * 8;
    const float* b1 = (const float*)(ws + OFF_B1) + e * 128;
    int wave = t >> 6, lane = t & 63, lr = lane & 15, lk = lane >> 4;

    f32x4 acc[4][2];
#pragma unroll
    for (int m = 0; m < 4; ++m)
#pragma unroll
        for (int n = 0; n < 2; ++n)
#pragma unroll
            for (int r = 0; r < 4; ++r) acc[m][n][r] = 0.f;

#pragma unroll
    for (int kf = 0; kf < 8; ++kf) {
        bf16x8 a[4], bb[2];
#pragma unroll
        for (int m = 0; m < 4; ++m)
            a[m] = *(const bf16x8*)(Alds + (((kf * 4 + lk) * 64) + (m * 16 + lr)) * 8);
#pragma unroll
        for (int n = 0; n < 2; ++n) {
            int colh = wave * 32 + n * 16 + lr;
            int kc = kf * 4 + lk;
            bb[n] = *(const bf16x8*)(PW1 + ((size_t)kc * 128 + colh) * 8);
        }
#pragma unroll
        for (int m = 0; m < 4; ++m)
#pragma unroll
            for (int n = 0; n < 2; ++n)
                acc[m][n] = __builtin_amdgcn_mfma_f32_16x16x32_bf16(a[m], bb[n], acc[m][n], 0, 0, 0);
    }
    __syncthreads();

#pragma unroll
    for (int m = 0; m < 4; ++m)
#pragma unroll
        for (int n = 0; n < 2; ++n) {
            int colh = wave * 32 + n * 16 + lr;
            float bbv = b1[colh];
#pragma unroll
            for (int r = 0; r < 4; ++r) {
                int row = m * 16 + lk * 4 + r;
                haF[colh * 66 + row] = tanh_(acc[m][n][r] + bbv);
            }
        }
    __syncthreads();

    int row = t & 63;
    int grow = rows_s[row];
    bool valid = row < nr;
#pragma unroll
    for (int p = 0; p < 5; ++p) {
        int aI = p * 4 + (t >> 6);
        if (aI < NA) {
            float s = ba2[e * NA + aI];
            for (int hh = 0; hh < 64; ++hh)
                s += haF[hh * 66 + row] * Wa2[((size_t)e * 64 + hh) * NA + aI];
            if (valid) lout[(size_t)grow * NA + aI] = s;
        }
    }
    if (t < 64) {
        float s = bc2[e];
        for (int hh = 0; hh < 64; ++hh)
            s += haF[(64 + hh) * 66 + row] * Wc2[e * 64 + hh];
        if (valid) vout[grow] = s;
    }
}

extern "C" void kernel_launch(void* const* d_in, const int* in_sizes, int n_in,
                              void* d_out, int out_size, void* d_ws, size_t ws_size,
                              hipStream_t stream) {
    const float* obs  = (const float*)d_in[0];
    const float* h    = (const float*)d_in[1];
    const float* c    = (const float*)d_in[2];
    const int*   idxs = (const int*)d_in[3];
    const float* W_ih = (const float*)d_in[4];
    const float* W_hh = (const float*)d_in[5];
    const float* b_ih = (const float*)d_in[6];
    const float* b_hh = (const float*)d_in[7];
    const float* Wa1  = (const float*)d_in[8];
    const float* ba1  = (const float*)d_in[9];
    const float* Wa2  = (const float*)d_in[10];
    const float* ba2  = (const float*)d_in[11];
    const float* Wc1  = (const float*)d_in[12];
    const float* bc1  = (const float*)d_in[13];
    const float* Wc2  = (const float*)d_in[14];
    const float* bc2  = (const float*)d_in[15];

    float* out  = (float*)d_out;
    float* hout = out;
    float* cout = out + (size_t)NB * ND;
    float* lout = out + (size_t)2 * NB * ND;
    float* vout = lout + (size_t)NB * NA;
    char* ws = (char*)d_ws;

    k_prep1<<<dim3(256), dim3(256), 0, stream>>>(W_ih, W_hh, b_ih, b_hh, ws);
    k_prep2<<<dim3(256), dim3(256), 0, stream>>>(Wa1, Wc1, ba1, bc1, ws);
    k_scatter<<<dim3(256), dim3(256), 0, stream>>>(idxs, ws);
    k_lstm<<<dim3(2048), dim3(512), 0, stream>>>(
        obs, h, c, (const float*)(ws + OFF_BCAT), (const bf16*)(ws + OFF_WCAT), hout, cout);
    k_expert<<<dim3(1024, 16), dim3(256), 0, stream>>>(
        Wa2, ba2, Wc2, bc2, ws, hout, lout, vout);
}